// Round 15
// baseline (81.672 us; speedup 1.0000x reference)
//
#include <hip/hip_runtime.h>
#include <hip/hip_fp16.h>

#define BB 16
#define NN 4096
#define CC 6
#define NSEG (BB * NN)          // 65536 points per direction-role
#define NTILE 128               // 4096 cols / 32
#define NBLK 1024               // min-kernel blocks

using half8  = __attribute__((ext_vector_type(8))) _Float16;

// ---- explicit-register asm inner loop ------------------------------------
// Fixed map (fits under the 128-reg budget of __launch_bounds__(256,4)):
//   zc v[32:47] | d0 v[48:63] | d1 v[64:79]
//   P tiles v[80:83][84:87][88:91][92:95]
//   Q tiles v[96:99][100:103][104:107][108:111]
//   addrP v[112:113]  addrQ v[114:115]
// B loads are exec-masked to lanes 0-31: lanes 32-63 feed MFMA K=8..15 which
// A's zero upper half annihilates — their tile regs are zero-initialized once
// and never written again (halves TD return bytes per load).
#define FOLD16 \
  "v_min3_f32 %[m0],  %[m0],  v48, v64\n\t" \
  "v_min3_f32 %[m1],  %[m1],  v49, v65\n\t" \
  "v_min3_f32 %[m2],  %[m2],  v50, v66\n\t" \
  "v_min3_f32 %[m3],  %[m3],  v51, v67\n\t" \
  "v_min3_f32 %[m4],  %[m4],  v52, v68\n\t" \
  "v_min3_f32 %[m5],  %[m5],  v53, v69\n\t" \
  "v_min3_f32 %[m6],  %[m6],  v54, v70\n\t" \
  "v_min3_f32 %[m7],  %[m7],  v55, v71\n\t" \
  "v_min3_f32 %[m8],  %[m8],  v56, v72\n\t" \
  "v_min3_f32 %[m9],  %[m9],  v57, v73\n\t" \
  "v_min3_f32 %[m10], %[m10], v58, v74\n\t" \
  "v_min3_f32 %[m11], %[m11], v59, v75\n\t" \
  "v_min3_f32 %[m12], %[m12], v60, v76\n\t" \
  "v_min3_f32 %[m13], %[m13], v61, v77\n\t" \
  "v_min3_f32 %[m14], %[m14], v62, v78\n\t" \
  "v_min3_f32 %[m15], %[m15], v63, v79\n\t"

#define PHASE(T0, T1, T2, T3, ALO, AHI, APAIR)                              \
  "s_waitcnt vmcnt(4)\n\t"                                                  \
  "v_mfma_f32_32x32x16_f16 v[48:63], %[fa], " T0 ", v[32:47]\n\t"           \
  "v_mfma_f32_32x32x16_f16 v[64:79], %[fa], " T1 ", v[32:47]\n\t"           \
  "v_add_co_u32 " ALO ", vcc, 0x1000, " ALO "\n\t"                          \
  "v_addc_co_u32 " AHI ", vcc, 0, " AHI ", vcc\n\t"                         \
  "s_nop 1\n\t"                                                             \
  "s_mov_b32 exec_hi, 0\n\t"                                                \
  "global_load_dwordx4 " T0 ", " APAIR ", off\n\t"                          \
  "global_load_dwordx4 " T1 ", " APAIR ", off offset:512\n\t"               \
  "s_mov_b32 exec_hi, -1\n\t"                                               \
  "s_nop 7\n\t"                                                             \
  "s_nop 7\n\t"                                                             \
  FOLD16                                                                    \
  "v_mfma_f32_32x32x16_f16 v[48:63], %[fa], " T2 ", v[32:47]\n\t"           \
  "v_mfma_f32_32x32x16_f16 v[64:79], %[fa], " T3 ", v[32:47]\n\t"           \
  "s_mov_b32 exec_hi, 0\n\t"                                                \
  "global_load_dwordx4 " T2 ", " APAIR ", off offset:1024\n\t"              \
  "global_load_dwordx4 " T3 ", " APAIR ", off offset:1536\n\t"              \
  "s_mov_b32 exec_hi, -1\n\t"                                               \
  "s_nop 7\n\t"                                                             \
  "s_nop 7\n\t"                                                             \
  "s_nop 4\n\t"                                                             \
  FOLD16

// ws layout:
//   half8 Af[2][BB][NN] @ 0     (2 MB) A entry per ROW point: (-2h0,-2h1,-2h2,1,1,0,0,0)
//   half8 Bf[2][BB][NN] @ 2 MB  (2 MB) B entry per COL point: ( h0, h1, h2,hi,lo,0,0,0)
//   float rx[2][BB][NN] @ 4 MB  (512 KB) row-point |h|^2 fp32 (absorbs tail over-read)
//   float bpart[NBLK]   @ 4.5MB (4 KB) per-block partials

__global__ __launch_bounds__(256) void chamfer_prep_kernel(
    const float* __restrict__ xg, const float* __restrict__ yg,
    half8* __restrict__ Af, half8* __restrict__ Bf, float* __restrict__ rx)
{
    const int p   = blockIdx.x * 256 + threadIdx.x;   // 0..131071
    const int dir = p >> 16;
    const int rem = p & (NSEG - 1);
    const float* __restrict__ R  = dir ? yg : xg;   // row cloud (min FOR its points)
    const float* __restrict__ Cl = dir ? xg : yg;   // col cloud (min OVER its points)

    {   // row side
        const float c0 = R[(size_t)rem * CC + 0];
        const float c1 = R[(size_t)rem * CC + 1];
        const float c2 = R[(size_t)rem * CC + 2];
        const _Float16 h0 = (_Float16)c0, h1 = (_Float16)c1, h2 = (_Float16)c2;
        const float f0 = (float)h0, f1 = (float)h1, f2 = (float)h2;
        rx[p] = fmaf(f0, f0, fmaf(f1, f1, f2 * f2));
        half8 a = { (_Float16)(-2.0f) * h0, (_Float16)(-2.0f) * h1,
                    (_Float16)(-2.0f) * h2, (_Float16)1.0f, (_Float16)1.0f,
                    (_Float16)0.0f, (_Float16)0.0f, (_Float16)0.0f };
        Af[p] = a;
    }
    {   // col side: ry as hi/lo fp16 pair in K-slots 3,4
        const float c0 = Cl[(size_t)rem * CC + 0];
        const float c1 = Cl[(size_t)rem * CC + 1];
        const float c2 = Cl[(size_t)rem * CC + 2];
        const _Float16 h0 = (_Float16)c0, h1 = (_Float16)c1, h2 = (_Float16)c2;
        const float f0 = (float)h0, f1 = (float)h1, f2 = (float)h2;
        const float r  = fmaf(f0, f0, fmaf(f1, f1, f2 * f2));
        const _Float16 hi = (_Float16)r;
        const _Float16 lo = (_Float16)(r - (float)hi);
        half8 bfr = { h0, h1, h2, hi, lo,
                      (_Float16)0.0f, (_Float16)0.0f, (_Float16)0.0f };
        Bf[p] = bfr;
    }
}

// grid = 1024 blocks x 256 thr (4 waves). wave -> (dir, b, rowgroup of 32); full j-range.
__global__ __launch_bounds__(256, 4) void chamfer_min_kernel(
    const half8* __restrict__ Af, const half8* __restrict__ Bf,
    const float* __restrict__ rx, float* __restrict__ bpart)
{
    const int bid  = blockIdx.x;
    const int dir  = bid & 1;
    const int b    = (bid >> 1) & 15;
    const int gq   = bid >> 5;                 // 0..31
    const int tid  = threadIdx.x;
    const int w    = tid >> 6;
    const int lane = tid & 63;
    const int l31  = lane & 31;
    const int hf   = lane >> 5;                // K-half select for A (upper = zeros)
    const int g    = gq * 4 + w;               // rowgroup 0..127

    const size_t base = ((size_t)dir << 16) + ((size_t)b << 12);

    half8 a = {};
    if (hf == 0) a = Af[base + (size_t)g * 32 + l31];   // one-time guarded load

    // per-lane byte address of this block's B stream (only lanes 0-31 load)
    const unsigned long long ba = (unsigned long long)(Bf + base + l31);
    const unsigned alo = (unsigned)ba;
    const unsigned ahi = (unsigned)(ba >> 32);

    float m0  = 3.4e38f, m1  = 3.4e38f, m2  = 3.4e38f, m3  = 3.4e38f;
    float m4  = 3.4e38f, m5  = 3.4e38f, m6  = 3.4e38f, m7  = 3.4e38f;
    float m8  = 3.4e38f, m9  = 3.4e38f, m10 = 3.4e38f, m11 = 3.4e38f;
    float m12 = 3.4e38f, m13 = 3.4e38f, m14 = 3.4e38f, m15 = 3.4e38f;
    int cnt = 16;

    asm volatile(
        // zero-C tile v[32:47], built once, never rewritten
        "v_mov_b32 v32, 0\n\t"  "v_mov_b32 v33, 0\n\t"
        "v_mov_b32 v34, 0\n\t"  "v_mov_b32 v35, 0\n\t"
        "v_mov_b32 v36, 0\n\t"  "v_mov_b32 v37, 0\n\t"
        "v_mov_b32 v38, 0\n\t"  "v_mov_b32 v39, 0\n\t"
        "v_mov_b32 v40, 0\n\t"  "v_mov_b32 v41, 0\n\t"
        "v_mov_b32 v42, 0\n\t"  "v_mov_b32 v43, 0\n\t"
        "v_mov_b32 v44, 0\n\t"  "v_mov_b32 v45, 0\n\t"
        "v_mov_b32 v46, 0\n\t"  "v_mov_b32 v47, 0\n\t"
        // zero ALL tile regs once: upper lanes are never loaded again, and
        // garbage there (NaN/Inf) would poison D via 0*NaN -> NaN.
        "v_mov_b32 v80, 0\n\t"  "v_mov_b32 v81, 0\n\t"
        "v_mov_b32 v82, 0\n\t"  "v_mov_b32 v83, 0\n\t"
        "v_mov_b32 v84, 0\n\t"  "v_mov_b32 v85, 0\n\t"
        "v_mov_b32 v86, 0\n\t"  "v_mov_b32 v87, 0\n\t"
        "v_mov_b32 v88, 0\n\t"  "v_mov_b32 v89, 0\n\t"
        "v_mov_b32 v90, 0\n\t"  "v_mov_b32 v91, 0\n\t"
        "v_mov_b32 v92, 0\n\t"  "v_mov_b32 v93, 0\n\t"
        "v_mov_b32 v94, 0\n\t"  "v_mov_b32 v95, 0\n\t"
        "v_mov_b32 v96, 0\n\t"  "v_mov_b32 v97, 0\n\t"
        "v_mov_b32 v98, 0\n\t"  "v_mov_b32 v99, 0\n\t"
        "v_mov_b32 v100, 0\n\t" "v_mov_b32 v101, 0\n\t"
        "v_mov_b32 v102, 0\n\t" "v_mov_b32 v103, 0\n\t"
        "v_mov_b32 v104, 0\n\t" "v_mov_b32 v105, 0\n\t"
        "v_mov_b32 v106, 0\n\t" "v_mov_b32 v107, 0\n\t"
        "v_mov_b32 v108, 0\n\t" "v_mov_b32 v109, 0\n\t"
        "v_mov_b32 v110, 0\n\t" "v_mov_b32 v111, 0\n\t"
        // addrP = ba ; addrQ = ba + 2048
        "v_mov_b32 v112, %[alo]\n\t"
        "v_mov_b32 v113, %[ahi]\n\t"
        "v_add_co_u32 v114, vcc, 0x800, v112\n\t"
        "v_addc_co_u32 v115, vcc, 0, v113, vcc\n\t"
        "s_nop 1\n\t"
        // preload P (tiles 0-3) and Q (tiles 4-7), lanes 0-31 only
        "s_mov_b32 exec_hi, 0\n\t"
        "global_load_dwordx4 v[80:83],   v[112:113], off\n\t"
        "global_load_dwordx4 v[84:87],   v[112:113], off offset:512\n\t"
        "global_load_dwordx4 v[88:91],   v[112:113], off offset:1024\n\t"
        "global_load_dwordx4 v[92:95],   v[112:113], off offset:1536\n\t"
        "global_load_dwordx4 v[96:99],   v[114:115], off\n\t"
        "global_load_dwordx4 v[100:103], v[114:115], off offset:512\n\t"
        "global_load_dwordx4 v[104:107], v[114:115], off offset:1024\n\t"
        "global_load_dwordx4 v[108:111], v[114:115], off offset:1536\n\t"
        "s_mov_b32 exec_hi, -1\n\t"
        "LOOP%=:\n\t"
        PHASE("v[80:83]", "v[84:87]", "v[88:91]", "v[92:95]",
              "v112", "v113", "v[112:113]")
        PHASE("v[96:99]", "v[100:103]", "v[104:107]", "v[108:111]",
              "v114", "v115", "v[114:115]")
        "s_sub_u32 %[cnt], %[cnt], 1\n\t"
        "s_cmp_lg_u32 %[cnt], 0\n\t"
        "s_cbranch_scc1 LOOP%=\n\t"
        "s_waitcnt vmcnt(0)"
        : [m0] "+v"(m0),  [m1] "+v"(m1),  [m2] "+v"(m2),  [m3] "+v"(m3),
          [m4] "+v"(m4),  [m5] "+v"(m5),  [m6] "+v"(m6),  [m7] "+v"(m7),
          [m8] "+v"(m8),  [m9] "+v"(m9),  [m10] "+v"(m10), [m11] "+v"(m11),
          [m12] "+v"(m12), [m13] "+v"(m13), [m14] "+v"(m14), [m15] "+v"(m15),
          [cnt] "+s"(cnt)
        : [fa] "v"(a), [alo] "v"(alo), [ahi] "v"(ahi)
        : "memory", "vcc", "scc",
          "v32","v33","v34","v35","v36","v37","v38","v39",
          "v40","v41","v42","v43","v44","v45","v46","v47",
          "v48","v49","v50","v51","v52","v53","v54","v55",
          "v56","v57","v58","v59","v60","v61","v62","v63",
          "v64","v65","v66","v67","v68","v69","v70","v71",
          "v72","v73","v74","v75","v76","v77","v78","v79",
          "v80","v81","v82","v83","v84","v85","v86","v87",
          "v88","v89","v90","v91","v92","v93","v94","v95",
          "v96","v97","v98","v99","v100","v101","v102","v103",
          "v104","v105","v106","v107","v108","v109","v110","v111",
          "v112","v113","v114","v115");

    float mn[16] = { m0, m1, m2, m3, m4, m5, m6, m7,
                     m8, m9, m10, m11, m12, m13, m14, m15 };

    // cross-lane min over the 32 cols within each half (halves hold different rows)
    #pragma unroll
    for (int s = 0; s < 16; ++s) {
        float v = mn[s];
        v = fminf(v, __shfl_xor(v, 1,  64));
        v = fminf(v, __shfl_xor(v, 2,  64));
        v = fminf(v, __shfl_xor(v, 4,  64));
        v = fminf(v, __shfl_xor(v, 8,  64));
        v = fminf(v, __shfl_xor(v, 16, 64));
        mn[s] = v;
    }

    // add rx per row, sum this half's 16 rows
    const float* __restrict__ rxb = rx + base + (size_t)g * 32;
    float s16 = 0.0f;
    #pragma unroll
    for (int s = 0; s < 16; ++s) {
        const int row = (s & 3) + 8 * (s >> 2) + 4 * hf;  // C/D row map (m101)
        s16 += fmaxf(mn[s] + rxb[row], 0.0f);             // clamp fp noise at 0
    }

    __shared__ float hsum[8];
    if (l31 == 0) hsum[w * 2 + hf] = s16;
    __syncthreads();
    if (tid == 0) {
        float t = 0.0f;
        #pragma unroll
        for (int k = 0; k < 8; ++k) t += hsum[k];
        bpart[bid] = t;            // plain store — no atomics anywhere
    }
}

__global__ __launch_bounds__(256) void chamfer_final_kernel(
    const float* __restrict__ bpart, float* __restrict__ out)
{
    const int tid = threadIdx.x;
    float s = bpart[tid] + bpart[tid + 256] + bpart[tid + 512] + bpart[tid + 768];
    for (int off = 32; off > 0; off >>= 1)
        s += __shfl_down(s, off, 64);
    __shared__ float wsum[4];
    if ((tid & 63) == 0) wsum[tid >> 6] = s;
    __syncthreads();
    if (tid == 0)
        out[0] = (wsum[0] + wsum[1] + wsum[2] + wsum[3]) * (1.0f / NSEG);
}

extern "C" void kernel_launch(void* const* d_in, const int* in_sizes, int n_in,
                              void* d_out, int out_size, void* d_ws, size_t ws_size,
                              hipStream_t stream) {
    const float* x = (const float*)d_in[0];
    const float* y = (const float*)d_in[1];
    float* out = (float*)d_out;

    half8* Af = (half8*)d_ws;
    half8* Bf = (half8*)((char*)d_ws + (size_t)2 * NSEG * sizeof(half8));
    float* rx = (float*)((char*)d_ws + (size_t)4 * NSEG * sizeof(half8));
    float* bpart = (float*)((char*)rx + (size_t)2 * NSEG * sizeof(float));

    chamfer_prep_kernel<<<2 * NSEG / 256, 256, 0, stream>>>(x, y, Af, Bf, rx);
    chamfer_min_kernel<<<NBLK, 256, 0, stream>>>(Af, Bf, rx, bpart);
    chamfer_final_kernel<<<1, 256, 0, stream>>>(bpart, out);
}